// Round 8
// baseline (520.212 us; speedup 1.0000x reference)
//
#include <hip/hip_runtime.h>
#include <hip/hip_bf16.h>
#include <math.h>

// Round 8: widen the phase-A prefetch window.
//  Round-7 state: spill gone (WRITE 573KB), FETCH at streaming ideal, but
//  VALUBusy 36% -> latency-bound in phase A: `#pragma unroll 5` gave the
//  scheduler only a 5-iter window over the 35 dependent float4 x-loads.
//  Single change: FULL unroll of the q-loop so the compiler hoists 10-15
//  loads (VGPR headroom 128-60) -> prefetch window >> HBM latency.

#define THREADS 256
#define SPB 25
#define NB 65536

__device__ __forceinline__ unsigned bfr(float f) {
    unsigned u = __float_as_uint(f);
    return (u + 0x7fffu + ((u >> 16) & 1u)) >> 16;   // RNE to bf16
}
__device__ __forceinline__ unsigned pack_bf(float a, float b) {
    return bfr(a) | (bfr(b) << 16);
}
__device__ __forceinline__ float bf_lo(unsigned u) { return __uint_as_float(u << 16); }
__device__ __forceinline__ float bf_hi(unsigned u) { return __uint_as_float(u & 0xffff0000u); }

__global__ __launch_bounds__(THREADS, 4) void fused_model_kernel(
    const float* __restrict__ x,
    const float* __restrict__ h_w1, const float* __restrict__ h_b1,
    const float* __restrict__ h_w2, const float* __restrict__ h_b2,
    const float* __restrict__ h_w3, const float* __restrict__ h_b3,
    const float* __restrict__ c_w1, const float* __restrict__ c_b1,
    const float* __restrict__ c_w2, const float* __restrict__ c_b2,
    const float* __restrict__ c_w3, const float* __restrict__ c_b3,
    const float* __restrict__ t_w1, const float* __restrict__ t_b1,
    const float* __restrict__ t_w2, const float* __restrict__ t_b2,
    const float* __restrict__ t_w3, const float* __restrict__ t_b3,
    const float* __restrict__ f_w1, const float* __restrict__ f_b1,
    const float* __restrict__ f_w2, const float* __restrict__ f_b2,
    const float* __restrict__ f_w3, const float* __restrict__ f_b3,
    float* __restrict__ out)
{
    // LDS arena: 7700 u32 = 30800 B.
    //  [0,2250)     ho32 u32 bf16x2, 250 rows x 9   (A..E1)
    //  [2250,6500)  uv32 u32 bf16x2, 250 rows x 17  (A..C)
    //     alias: h1t [2250,3900) 50x33 (E1..E2), h2t [3900,5550) (E2..E3)
    //  [6500,7500)  sPm  f32 25*2*5*4 (C..D);  alias sT f32 25x33 (E3..F)
    //  [7500,7700)  sG   f32 25x8 (D..E1)
    __shared__ unsigned smem_u[7700];
    unsigned* const ho32 = smem_u;
    unsigned* const uv32 = smem_u + 2250;
    unsigned* const h1t  = smem_u + 2250;
    unsigned* const h2t  = smem_u + 3900;
    float*    const sPm  = (float*)(smem_u + 6500);
    float*    const sT   = (float*)(smem_u + 6500);
    float*    const sG   = (float*)(smem_u + 7500);

    const int tid = threadIdx.x;
    const int wg  = blockIdx.x;
    const int s0  = wg * SPB;
    const int vs  = (NB - s0 < SPB) ? (NB - s0) : SPB;
    const int vr  = vs * 10;

    // ===== Phase A: hero chain + u/v, one row per lane, weights in SGPRs =====
    if (tid < vr) {
        const float* xr = x + ((size_t)s0 * 10 + tid) * 140;
        float acc[32];
        #pragma unroll
        for (int o = 0; o < 32; ++o) acc[o] = h_b1[o];
        #pragma unroll
        for (int q = 0; q < 35; ++q) {      // FULL unroll: max load-hoist window
            const float4 xv = *(const float4*)(xr + q * 4);
            const float* w0 = h_w1 + (q * 4 + 0) * 32;
            const float* w1 = h_w1 + (q * 4 + 1) * 32;
            const float* w2 = h_w1 + (q * 4 + 2) * 32;
            const float* w3 = h_w1 + (q * 4 + 3) * 32;
            #pragma unroll
            for (int o = 0; o < 32; ++o) {
                float a = fmaf(xv.x, w0[o], acc[o]);
                a = fmaf(xv.y, w1[o], a);
                a = fmaf(xv.z, w2[o], a);
                acc[o] = fmaf(xv.w, w3[o], a);
            }
        }
        #pragma unroll
        for (int o = 0; o < 32; ++o) acc[o] = fmaxf(acc[o], 0.f);

        // layer 2 (32->32) -- FULL unroll (acc[k] static-indexed)
        float a2[32];
        #pragma unroll
        for (int o = 0; o < 32; ++o) a2[o] = h_b2[o];
        #pragma unroll
        for (int k = 0; k < 32; ++k) {
            const float hk = acc[k];
            const float* wr = h_w2 + k * 32;
            #pragma unroll
            for (int o = 0; o < 32; ++o) a2[o] = fmaf(hk, wr[o], a2[o]);
        }
        #pragma unroll
        for (int o = 0; o < 32; ++o) a2[o] = fmaxf(a2[o], 0.f);

        // layer 3 (32->16, linear) -- FULL unroll (a2[k])
        float ho[16];
        #pragma unroll
        for (int o = 0; o < 16; ++o) ho[o] = h_b3[o];
        #pragma unroll
        for (int k = 0; k < 32; ++k) {
            const float hk = a2[k];
            const float* wr = h_w3 + k * 16;
            #pragma unroll
            for (int o = 0; o < 16; ++o) ho[o] = fmaf(hk, wr[o], ho[o]);
        }

        // u = ho @ cW1[:16], v = ho @ cW1[16:] -- FULL unroll (ho[k])
        float u[16], v[16];
        #pragma unroll
        for (int o = 0; o < 16; ++o) { u[o] = 0.f; v[o] = 0.f; }
        #pragma unroll
        for (int k = 0; k < 16; ++k) {
            const float hk = ho[k];
            const float* wu = c_w1 + k * 16;
            const float* wv = c_w1 + (16 + k) * 16;
            #pragma unroll
            for (int o = 0; o < 16; ++o) {
                u[o] = fmaf(hk, wu[o], u[o]);
                v[o] = fmaf(hk, wv[o], v[o]);
            }
        }

        #pragma unroll
        for (int cc = 0; cc < 8; ++cc)
            ho32[tid * 9 + cc] = pack_bf(ho[2 * cc], ho[2 * cc + 1]);
        #pragma unroll
        for (int cc = 0; cc < 8; ++cc) {
            uv32[tid * 17 + cc]     = pack_bf(u[2 * cc], u[2 * cc + 1]);
            uv32[tid * 17 + 8 + cc] = pack_bf(v[2 * cc], v[2 * cc + 1]);
        }
    }
    __syncthreads();

    // ===== Phase C: 50 pairs/sample, counter L2/L3 + pool2, 10 lanes/sample =====
    if (tid < vs * 10) {
        const int s = tid / 10;
        const int t10 = tid % 10;
        const int half = t10 / 5;
        const int pg = t10 % 5;
        float pm0 = -1e30f, pm1 = -1e30f, pm2 = -1e30f, pm3 = -1e30f;
        for (int n = 0; n < 5; ++n) {
            int i, j;
            if (half == 0) { i = pg; j = 5 + n; } else { i = 5 + pg; j = n; }
            const unsigned* ur  = uv32 + (s * 10 + i) * 17;
            const unsigned* vrw = uv32 + (s * 10 + j) * 17 + 8;
            float h1p[16];
            #pragma unroll
            for (int cc = 0; cc < 8; ++cc) {
                const unsigned uu = ur[cc], vv = vrw[cc];
                h1p[2 * cc]     = fmaxf(bf_lo(uu) + bf_lo(vv) + c_b1[2 * cc], 0.f);
                h1p[2 * cc + 1] = fmaxf(bf_hi(uu) + bf_hi(vv) + c_b1[2 * cc + 1], 0.f);
            }
            float a[16];
            #pragma unroll
            for (int o = 0; o < 16; ++o) a[o] = c_b2[o];
            #pragma unroll
            for (int k = 0; k < 16; ++k) {
                const float hk = h1p[k];
                const float* wr = c_w2 + k * 16;
                #pragma unroll
                for (int o = 0; o < 16; ++o) a[o] = fmaf(hk, wr[o], a[o]);
            }
            float c3[8];
            #pragma unroll
            for (int o = 0; o < 8; ++o) c3[o] = c_b3[o];
            #pragma unroll
            for (int k = 0; k < 16; ++k) {
                const float hk = fmaxf(a[k], 0.f);
                const float* wr = c_w3 + k * 8;
                #pragma unroll
                for (int o = 0; o < 8; ++o) c3[o] = fmaf(hk, wr[o], c3[o]);
            }
            pm0 = fmaxf(pm0, fmaxf(c3[0], c3[1]));
            pm1 = fmaxf(pm1, fmaxf(c3[2], c3[3]));
            pm2 = fmaxf(pm2, fmaxf(c3[4], c3[5]));
            pm3 = fmaxf(pm3, fmaxf(c3[6], c3[7]));
        }
        float* dst = sPm + ((s * 2 + half) * 5 + pg) * 4;
        dst[0] = pm0; dst[1] = pm1; dst[2] = pm2; dst[3] = pm3;
    }
    __syncthreads();

    // ===== Phase D: max over 5 groups -> g =====
    if (tid < vs * 8) {
        const int s = tid >> 3;
        const int r = tid & 7;            // half*4 + m
        const int half = r >> 2, m = r & 3;
        float mx = -1e30f;
        #pragma unroll
        for (int pg = 0; pg < 5; ++pg)
            mx = fmaxf(mx, sPm[((s * 2 + half) * 5 + pg) * 4 + m]);
        sG[s * 8 + r] = mx;
    }
    __syncthreads();

    // ===== Phase E1: team layer 1 (84 -> 64), 4 lanes/row =====
    if (tid < vs * 8) {
        const int s = tid >> 3;
        const int half = (tid >> 2) & 1;
        const int q = tid & 3;
        const int o0 = q * 16;
        float a[16];
        #pragma unroll
        for (int o = 0; o < 16; ++o) a[o] = t_b1[o0 + o];
        for (int h5 = 0; h5 < 5; ++h5) {
            const int row = s * 10 + half * 5 + h5;
            #pragma unroll
            for (int cc = 0; cc < 8; ++cc) {
                const unsigned hv = ho32[row * 9 + cc];
                const float x0 = bf_lo(hv), x1 = bf_hi(hv);
                const int k0 = h5 * 16 + 2 * cc;
                #pragma unroll
                for (int ob = 0; ob < 4; ++ob) {
                    const float4 w0 = *(const float4*)(t_w1 + k0 * 64 + o0 + ob * 4);
                    const float4 w1 = *(const float4*)(t_w1 + (k0 + 1) * 64 + o0 + ob * 4);
                    a[ob * 4 + 0] = fmaf(x0, w0.x, a[ob * 4 + 0]);
                    a[ob * 4 + 1] = fmaf(x0, w0.y, a[ob * 4 + 1]);
                    a[ob * 4 + 2] = fmaf(x0, w0.z, a[ob * 4 + 2]);
                    a[ob * 4 + 3] = fmaf(x0, w0.w, a[ob * 4 + 3]);
                    a[ob * 4 + 0] = fmaf(x1, w1.x, a[ob * 4 + 0]);
                    a[ob * 4 + 1] = fmaf(x1, w1.y, a[ob * 4 + 1]);
                    a[ob * 4 + 2] = fmaf(x1, w1.z, a[ob * 4 + 2]);
                    a[ob * 4 + 3] = fmaf(x1, w1.w, a[ob * 4 + 3]);
                }
            }
        }
        #pragma unroll
        for (int m = 0; m < 4; ++m) {
            const float gv = sG[s * 8 + half * 4 + m];
            #pragma unroll
            for (int ob = 0; ob < 4; ++ob) {
                const float4 w = *(const float4*)(t_w1 + (80 + m) * 64 + o0 + ob * 4);
                a[ob * 4 + 0] = fmaf(gv, w.x, a[ob * 4 + 0]);
                a[ob * 4 + 1] = fmaf(gv, w.y, a[ob * 4 + 1]);
                a[ob * 4 + 2] = fmaf(gv, w.z, a[ob * 4 + 2]);
                a[ob * 4 + 3] = fmaf(gv, w.w, a[ob * 4 + 3]);
            }
        }
        const int row48 = s * 2 + half;
        #pragma unroll
        for (int cc = 0; cc < 8; ++cc)
            h1t[row48 * 33 + q * 8 + cc] =
                pack_bf(fmaxf(a[2 * cc], 0.f), fmaxf(a[2 * cc + 1], 0.f));
    }
    __syncthreads();

    // ===== Phase E2: team layer 2 (64 -> 64) =====
    if (tid < vs * 8) {
        const int s = tid >> 3;
        const int half = (tid >> 2) & 1;
        const int q = tid & 3;
        const int o0 = q * 16;
        const int row48 = s * 2 + half;
        float a[16];
        #pragma unroll
        for (int o = 0; o < 16; ++o) a[o] = t_b2[o0 + o];
        #pragma unroll 8
        for (int cc = 0; cc < 32; ++cc) {   // h1t is LDS (addressable): ok partial
            const unsigned hv = h1t[row48 * 33 + cc];
            const float x0 = bf_lo(hv), x1 = bf_hi(hv);
            #pragma unroll
            for (int ob = 0; ob < 4; ++ob) {
                const float4 w0 = *(const float4*)(t_w2 + (2 * cc) * 64 + o0 + ob * 4);
                const float4 w1 = *(const float4*)(t_w2 + (2 * cc + 1) * 64 + o0 + ob * 4);
                a[ob * 4 + 0] = fmaf(x0, w0.x, a[ob * 4 + 0]);
                a[ob * 4 + 1] = fmaf(x0, w0.y, a[ob * 4 + 1]);
                a[ob * 4 + 2] = fmaf(x0, w0.z, a[ob * 4 + 2]);
                a[ob * 4 + 3] = fmaf(x0, w0.w, a[ob * 4 + 3]);
                a[ob * 4 + 0] = fmaf(x1, w1.x, a[ob * 4 + 0]);
                a[ob * 4 + 1] = fmaf(x1, w1.y, a[ob * 4 + 1]);
                a[ob * 4 + 2] = fmaf(x1, w1.z, a[ob * 4 + 2]);
                a[ob * 4 + 3] = fmaf(x1, w1.w, a[ob * 4 + 3]);
            }
        }
        #pragma unroll
        for (int cc = 0; cc < 8; ++cc)
            h2t[row48 * 33 + q * 8 + cc] =
                pack_bf(fmaxf(a[2 * cc], 0.f), fmaxf(a[2 * cc + 1], 0.f));
    }
    __syncthreads();

    // ===== Phase E3: team layer 3 (64 -> 16, linear) =====
    if (tid < vs * 8) {
        const int s = tid >> 3;
        const int half = (tid >> 2) & 1;
        const int q = tid & 3;
        const int o0 = q * 4;
        const int row48 = s * 2 + half;
        float a0 = t_b3[o0], a1 = t_b3[o0 + 1], a2 = t_b3[o0 + 2], a3 = t_b3[o0 + 3];
        #pragma unroll 8
        for (int cc = 0; cc < 32; ++cc) {   // h2t is LDS: ok partial
            const unsigned hv = h2t[row48 * 33 + cc];
            const float x0 = bf_lo(hv), x1 = bf_hi(hv);
            const float4 w0 = *(const float4*)(t_w3 + (2 * cc) * 16 + o0);
            const float4 w1 = *(const float4*)(t_w3 + (2 * cc + 1) * 16 + o0);
            a0 = fmaf(x0, w0.x, a0); a1 = fmaf(x0, w0.y, a1);
            a2 = fmaf(x0, w0.z, a2); a3 = fmaf(x0, w0.w, a3);
            a0 = fmaf(x1, w1.x, a0); a1 = fmaf(x1, w1.y, a1);
            a2 = fmaf(x1, w1.z, a2); a3 = fmaf(x1, w1.w, a3);
        }
        float* dst = sT + s * 33 + half * 16 + o0;
        dst[0] = a0; dst[1] = a1; dst[2] = a2; dst[3] = a3;
    }
    __syncthreads();

    // ===== Phase F: final MLP (32->16->16->2) + softmax, 1 lane/sample =====
    if (tid < vs) {
        const float* tr = sT + tid * 33;
        float g1[16];
        #pragma unroll
        for (int o = 0; o < 16; ++o) g1[o] = f_b1[o];
        #pragma unroll
        for (int k = 0; k < 32; ++k) {      // tr is LDS, g1 static-indexed
            const float hk = tr[k];
            const float* wr = f_w1 + k * 16;
            #pragma unroll
            for (int o = 0; o < 16; ++o) g1[o] = fmaf(hk, wr[o], g1[o]);
        }
        float g2[16];
        #pragma unroll
        for (int o = 0; o < 16; ++o) g2[o] = f_b2[o];
        #pragma unroll
        for (int k = 0; k < 16; ++k) {      // FULL unroll: g1[k]
            const float hk = fmaxf(g1[k], 0.f);
            const float* wr = f_w2 + k * 16;
            #pragma unroll
            for (int o = 0; o < 16; ++o) g2[o] = fmaf(hk, wr[o], g2[o]);
        }
        float l0 = f_b3[0], l1 = f_b3[1];
        #pragma unroll
        for (int k = 0; k < 16; ++k) {      // FULL unroll: g2[k]
            const float hk = fmaxf(g2[k], 0.f);
            l0 = fmaf(hk, f_w3[2 * k], l0);
            l1 = fmaf(hk, f_w3[2 * k + 1], l1);
        }
        const float e = expf(l1 - l0);
        const float p0 = 1.f / (1.f + e);
        out[(size_t)(s0 + tid) * 2]     = p0;
        out[(size_t)(s0 + tid) * 2 + 1] = 1.f - p0;
    }
}

extern "C" void kernel_launch(void* const* d_in, const int* in_sizes, int n_in,
                              void* d_out, int out_size, void* d_ws, size_t ws_size,
                              hipStream_t stream) {
    (void)in_sizes; (void)n_in; (void)d_ws; (void)ws_size; (void)out_size;
    const float* x    = (const float*)d_in[0];
    const float* h_w1 = (const float*)d_in[1];  const float* h_b1 = (const float*)d_in[2];
    const float* h_w2 = (const float*)d_in[3];  const float* h_b2 = (const float*)d_in[4];
    const float* h_w3 = (const float*)d_in[5];  const float* h_b3 = (const float*)d_in[6];
    const float* c_w1 = (const float*)d_in[7];  const float* c_b1 = (const float*)d_in[8];
    const float* c_w2 = (const float*)d_in[9];  const float* c_b2 = (const float*)d_in[10];
    const float* c_w3 = (const float*)d_in[11]; const float* c_b3 = (const float*)d_in[12];
    const float* t_w1 = (const float*)d_in[13]; const float* t_b1 = (const float*)d_in[14];
    const float* t_w2 = (const float*)d_in[15]; const float* t_b2 = (const float*)d_in[16];
    const float* t_w3 = (const float*)d_in[17]; const float* t_b3 = (const float*)d_in[18];
    const float* f_w1 = (const float*)d_in[19]; const float* f_b1 = (const float*)d_in[20];
    const float* f_w2 = (const float*)d_in[21]; const float* f_b2 = (const float*)d_in[22];
    const float* f_w3 = (const float*)d_in[23]; const float* f_b3 = (const float*)d_in[24];
    float* out = (float*)d_out;

    const int grid = (NB + SPB - 1) / SPB;   // 2622 workgroups
    fused_model_kernel<<<grid, THREADS, 0, stream>>>(
        x, h_w1, h_b1, h_w2, h_b2, h_w3, h_b3,
        c_w1, c_b1, c_w2, c_b2, c_w3, c_b3,
        t_w1, t_b1, t_w2, t_b2, t_w3, t_b3,
        f_w1, f_b1, f_w2, f_b2, f_w3, f_b3,
        out);
}